// Round 5
// baseline (2266.544 us; speedup 1.0000x reference)
//
#include <hip/hip_runtime.h>

#define BH   32      // B*H
#define NN   4096
#define DD   64
#define CC   64      // chunk rows
#define NCH  64      // NN/CC
#define NL   4
#define EPSF 1e-6f

// ---- swizzled LDS addressing: row stride 64 floats, float4-granular XOR swizzle.
__device__ __forceinline__ int swz(int row, int d) {
    return (row << 6) + ((((d >> 2) ^ (row & 7)) << 2) | (d & 3));
}
__device__ __forceinline__ int swz4(int row, int d0) {   // d0 % 4 == 0
    return (row << 6) + (((d0 >> 2) ^ (row & 7)) << 2);
}
__device__ __forceinline__ float elu1(float x) { return x > 0.f ? x + 1.f : __expf(x); }

// load 64x64 fp32 tile (global, row-major, 16B aligned) into swizzled LDS
__device__ __forceinline__ void load_tile(const float* __restrict__ g, float* buf, int t) {
    for (int m4 = t; m4 < 1024; m4 += 512) {
        int i = m4 >> 4, q = m4 & 15;
        *(float4*)(buf + (i << 6) + ((q ^ (i & 7)) << 2)) = ((const float4*)g)[m4];
    }
}
// inverse: swizzled LDS tile -> global row-major
__device__ __forceinline__ void store_tile(float* __restrict__ g, const float* buf, int t) {
    for (int m4 = t; m4 < 1024; m4 += 512) {
        int i = m4 >> 4, q = m4 & 15;
        ((float4*)g)[m4] = *(const float4*)(buf + (i << 6) + ((q ^ (i & 7)) << 2));
    }
}

// in-place running block-sum update: S_l -> S_{l+1}  (half = 2^l)
__device__ __forceinline__ void update_sums(float* KS, float* VS, int t, int half) {
    for (int m = t; m < 4096; m += 512) {
        int i = m >> 6, d = m & 63;
        if (i & half) {
            int idx = (i & ~(2 * half - 1)) | (half - 1);
            KS[swz(i, d)] += KS[swz(idx, d)];
            VS[swz(i, d)] += VS[swz(idx, d)];
        }
    }
}

// XP[i][e] = (elu?) ( (1/len_i) * sum_d XS[i][d] * W[e][d] )
__device__ __forceinline__ void project(const float* XS, const float* W, float* XP,
                                        int t, int half, bool do_elu) {
    int e = t & 63, w = t >> 6;
    float acc[8];
#pragma unroll
    for (int s = 0; s < 8; ++s) acc[s] = 0.f;
    for (int d0 = 0; d0 < 64; d0 += 4) {
        float4 wf = *(const float4*)(W + swz4(e, d0));       // per-lane row read
#pragma unroll
        for (int s = 0; s < 8; ++s) {
            float4 xf = *(const float4*)(XS + swz4(w + 8 * s, d0));  // broadcast
            acc[s] += xf.x * wf.x + xf.y * wf.y + xf.z * wf.z + xf.w * wf.w;
        }
    }
#pragma unroll
    for (int s = 0; s < 8; ++s) {
        int i = w + 8 * s;
        float rl = 1.f / (float)((i & (2 * half - 1)) + 1);
        float pv = acc[s] * rl;
        XP[swz(i, e)] = do_elu ? elu1(pv) : pv;
    }
}

// ---------------- Phase A: per-(bh,chunk) level-fused KV & k chunk sums ----------------
// write_proj: also materialize KP/VP tiles to wkp/wvp (FULL path)
__global__ __launch_bounds__(512) void phaseA(const float* __restrict__ k,
                                              const float* __restrict__ v,
                                              const float* __restrict__ Wk,
                                              const float* __restrict__ Wv,
                                              float* __restrict__ wskv,
                                              float* __restrict__ wsk,
                                              float* __restrict__ wkp,
                                              float* __restrict__ wvp,
                                              int lbase, int nlev, int write_proj) {
    __shared__ __align__(16) float KS[4096], VS[4096], KP[4096], VP[4096], WW[4096];
    int t = threadIdx.x;
    int bh = blockIdx.x >> 6, c = blockIdx.x & 63;
    const size_t cb = ((size_t)bh * NN + (size_t)c * CC) * DD;
    load_tile(k + cb, KS, t);
    load_tile(v + cb, VS, t);
    __syncthreads();
    for (int lp = 0; lp < lbase; ++lp) { update_sums(KS, VS, t, 1 << lp); __syncthreads(); }
    for (int li = 0; li < nlev; ++li) {
        int l = lbase + li;
        update_sums(KS, VS, t, 1 << l); __syncthreads();
        load_tile(Wk + (size_t)l * 4096, WW, t); __syncthreads();
        project(KS, WW, KP, t, 1 << l, true);  __syncthreads();
        if (write_proj) store_tile(wkp + ((size_t)(li * BH + bh) * NN + (size_t)c * CC) * DD, KP, t);
        load_tile(Wv + (size_t)l * 4096, WW, t); __syncthreads();
        project(VS, WW, VP, t, 1 << l, false); __syncthreads();
        if (write_proj) store_tile(wvp + ((size_t)(li * BH + bh) * NN + (size_t)c * CC) * DD, VP, t);
        // chunk sums: KVt[e][d] = sum_i KP[i][d]*VP[i][e];  ksum[d] = sum_i KP[i][d]
        int d = t & 63, eg = t >> 6;
        float acc[8];
#pragma unroll
        for (int u = 0; u < 8; ++u) acc[u] = 0.f;
        float ks = 0.f;
        for (int i = 0; i < 64; ++i) {
            float kp = KP[swz(i, d)];
            float4 va = *(const float4*)(VP + swz4(i, eg * 8));      // broadcast
            float4 vb = *(const float4*)(VP + swz4(i, eg * 8 + 4));  // broadcast
            acc[0] += kp * va.x; acc[1] += kp * va.y; acc[2] += kp * va.z; acc[3] += kp * va.w;
            acc[4] += kp * vb.x; acc[5] += kp * vb.y; acc[6] += kp * vb.z; acc[7] += kp * vb.w;
            ks += kp;
        }
        size_t kvb = ((((size_t)li * BH + bh) * NCH) + c) << 12;
#pragma unroll
        for (int u = 0; u < 8; ++u) wskv[kvb + (size_t)(eg * 8 + u) * 64 + d] = acc[u];
        if (eg == 0) wsk[(((size_t)li * BH + bh) * NCH + c) * 64 + d] = ks;
        __syncthreads();
    }
}

// ---------------- Phase B: exclusive prefix over chunks (in place) ----------------
__global__ __launch_bounds__(512) void phaseB(float* __restrict__ wskv, float* __restrict__ wsk) {
    int lbh = blockIdx.x >> 3, s = blockIdx.x & 7;
    size_t base = ((size_t)lbh << 18) + ((size_t)s << 9) + threadIdx.x;
    float run = 0.f;
    for (int c = 0; c < 64; ++c) {
        size_t a = base + ((size_t)c << 12);
        float vv = wskv[a];
        wskv[a] = run;
        run += vv;
    }
    if (s == 0 && threadIdx.x < 64) {
        size_t b2 = ((size_t)lbh << 12) + threadIdx.x;
        float r2 = 0.f;
        for (int c = 0; c < 64; ++c) {
            size_t a = b2 + (size_t)(c << 6);
            float vv = wsk[a];
            wsk[a] = r2;
            r2 += vv;
        }
    }
}

// ---------------- Phase C2 (FULL path): lean output kernel, 49.4 KB LDS, 3 WG/CU --------
__global__ __launch_bounds__(512) void phaseC2(const float* __restrict__ q,
                                               const float* __restrict__ sweights,
                                               const float* __restrict__ wskv,
                                               const float* __restrict__ wsk,
                                               const float* __restrict__ wkp,
                                               const float* __restrict__ wvp,
                                               float* __restrict__ out) {
    __shared__ __align__(16) float QP[4096], KP[4096], VP[4096];  // KP becomes AA after A-GEMM
    __shared__ __align__(16) float zz[64];
    int t = threadIdx.x;
    int bh = blockIdx.x >> 6, c = blockIdx.x & 63;
    const size_t cb = ((size_t)bh * NN + (size_t)c * CC) * DD;
    // qp = elu(q)+1, swizzled into LDS
    for (int m4 = t; m4 < 1024; m4 += 512) {
        int i = m4 >> 4, qq = m4 & 15;
        float4 g = ((const float4*)(q + cb))[m4];
        g.x = elu1(g.x); g.y = elu1(g.y); g.z = elu1(g.z); g.w = elu1(g.w);
        *(float4*)(QP + (i << 6) + ((qq ^ (i & 7)) << 2)) = g;
    }
    // softmax of scale weights in registers (redundant per thread, L2-hot)
    float s0 = sweights[0], s1 = sweights[1], s2 = sweights[2], s3 = sweights[3];
    float mx = fmaxf(fmaxf(s0, s1), fmaxf(s2, s3));
    float e0 = __expf(s0 - mx), e1 = __expf(s1 - mx), e2 = __expf(s2 - mx), e3 = __expf(s3 - mx);
    float inv = 1.f / (e0 + e1 + e2 + e3);
    float swl4[4] = {e0 * inv, e1 * inv, e2 * inv, e3 * inv};
    int e = t & 63, w = t >> 6;
    float oacc[8];
#pragma unroll
    for (int s = 0; s < 8; ++s) oacc[s] = 0.f;
    __syncthreads();
    for (int l = 0; l < NL; ++l) {
        float swl = swl4[l];
        size_t pb = ((size_t)(l * BH + bh) * NN + (size_t)c * CC) * DD;
        load_tile(wkp + pb, KP, t);
        load_tile(wvp + pb, VP, t);
        if (t < 16) *(float4*)(zz + t * 4) =
            *(const float4*)(wsk + (((size_t)l * BH + bh) * NCH + c) * 64 + t * 4);
        __syncthreads();
        // merged GEMM: A (QP·KP^T, col j=e), S·q (S^T row e from global), q·z
        const float* Sg = wskv + ((((size_t)l * BH + bh) * NCH + c) << 12) + e * 64;
        float a8[8], acc[8], nrm[8];
#pragma unroll
        for (int s = 0; s < 8; ++s) { a8[s] = 0.f; acc[s] = 0.f; nrm[s] = 0.f; }
        for (int d0 = 0; d0 < 64; d0 += 4) {
            float4 kf = *(const float4*)(KP + swz4(e, d0));       // per-lane row j=e
            float4 sf = *(const float4*)(Sg + d0);                // global, per-lane row e
            float4 zf = *(const float4*)(zz + d0);                // LDS broadcast
#pragma unroll
            for (int s = 0; s < 8; ++s) {
                float4 qf = *(const float4*)(QP + swz4(w + 8 * s, d0));  // broadcast
                a8[s]  += qf.x * kf.x + qf.y * kf.y + qf.z * kf.z + qf.w * kf.w;
                acc[s] += qf.x * sf.x + qf.y * sf.y + qf.z * sf.z + qf.w * sf.w;
                nrm[s] += qf.x * zf.x + qf.y * zf.y + qf.z * zf.z + qf.w * zf.w;
            }
        }
        __syncthreads();   // all KP reads done; safe to overwrite with AA
#pragma unroll
        for (int s = 0; s < 8; ++s) { int i = w + 8 * s; KP[swz(i, e)] = (e <= i) ? a8[s] : 0.f; }
        __syncthreads();   // AA visible
        // A·V + rowsum(A) folded (upper triangle zero-padded)
        for (int j0 = 0; j0 < 64; j0 += 4) {
            float v0 = VP[swz(j0, e)], v1 = VP[swz(j0 + 1, e)];
            float v2 = VP[swz(j0 + 2, e)], v3 = VP[swz(j0 + 3, e)];
#pragma unroll
            for (int s = 0; s < 8; ++s) {
                int i = w + 8 * s;
                if (j0 <= i) {                                    // wave-uniform
                    float4 af = *(const float4*)(KP + swz4(i, j0));  // broadcast (AA row)
                    acc[s] += af.x * v0 + af.y * v1 + af.z * v2 + af.w * v3;
                    nrm[s] += (af.x + af.y) + (af.z + af.w);
                }
            }
        }
#pragma unroll
        for (int s = 0; s < 8; ++s) oacc[s] += swl * (acc[s] / fmaxf(nrm[s], EPSF));
        __syncthreads();   // before next level's staging overwrites KP/VP
    }
#pragma unroll
    for (int s = 0; s < 8; ++s) out[cb + (size_t)(w + 8 * s) * 64 + e] = oacc[s];
}

// ---------------- Phase C (MED/SPLIT fallback): round-3 proven kernel ----------------
__global__ __launch_bounds__(512) void phaseC(const float* __restrict__ q,
                                              const float* __restrict__ k,
                                              const float* __restrict__ v,
                                              const float* __restrict__ Wk,
                                              const float* __restrict__ Wv,
                                              const float* __restrict__ sweights,
                                              const float* __restrict__ wskv,
                                              const float* __restrict__ wsk,
                                              float* __restrict__ out,
                                              int lbase, int nlev, int accum) {
    __shared__ __align__(16) float QP[4096], KS[4096], VS[4096], KP[4096], VP[4096], WW[4096], AA[4096];
    __shared__ __align__(16) float zz[64];
    __shared__ float nrmT[64];
    __shared__ float swsh[NL];
    int t = threadIdx.x;
    int bh = blockIdx.x >> 6, c = blockIdx.x & 63;
    const size_t cb = ((size_t)bh * NN + (size_t)c * CC) * DD;
    for (int m4 = t; m4 < 1024; m4 += 512) {
        int i = m4 >> 4, qq = m4 & 15;
        float4 g = ((const float4*)(q + cb))[m4];
        g.x = elu1(g.x); g.y = elu1(g.y); g.z = elu1(g.z); g.w = elu1(g.w);
        *(float4*)(QP + (i << 6) + ((qq ^ (i & 7)) << 2)) = g;
    }
    load_tile(k + cb, KS, t);
    load_tile(v + cb, VS, t);
    if (t == 0) {
        float s0 = sweights[0], s1 = sweights[1], s2 = sweights[2], s3 = sweights[3];
        float mx = fmaxf(fmaxf(s0, s1), fmaxf(s2, s3));
        float e0 = __expf(s0 - mx), e1 = __expf(s1 - mx), e2 = __expf(s2 - mx), e3 = __expf(s3 - mx);
        float inv = 1.f / (e0 + e1 + e2 + e3);
        swsh[0] = e0 * inv; swsh[1] = e1 * inv; swsh[2] = e2 * inv; swsh[3] = e3 * inv;
    }
    int e = t & 63, w = t >> 6;
    float oacc[8];
    if (accum) {
#pragma unroll
        for (int s = 0; s < 8; ++s) oacc[s] = out[cb + (size_t)(w + 8 * s) * 64 + e];
    } else {
#pragma unroll
        for (int s = 0; s < 8; ++s) oacc[s] = 0.f;
    }
    __syncthreads();
    for (int lp = 0; lp < lbase; ++lp) { update_sums(KS, VS, t, 1 << lp); __syncthreads(); }
    for (int li = 0; li < nlev; ++li) {
        int l = lbase + li;
        float swl = swsh[l];
        update_sums(KS, VS, t, 1 << l); __syncthreads();
        load_tile(Wk + (size_t)l * 4096, WW, t); __syncthreads();
        project(KS, WW, KP, t, 1 << l, true);  __syncthreads();
        load_tile(Wv + (size_t)l * 4096, WW, t); __syncthreads();
        project(VS, WW, VP, t, 1 << l, false); __syncthreads();
        size_t kvb = ((((size_t)li * BH + bh) * NCH) + c) << 12;
        for (int m4 = t; m4 < 1024; m4 += 512) {
            int ee = m4 >> 4, qq = m4 & 15;
            *(float4*)(WW + (ee << 6) + ((qq ^ (ee & 7)) << 2)) = *(const float4*)(wskv + kvb + ((size_t)m4 << 2));
        }
        if (t < 16) *(float4*)(zz + t * 4) =
            *(const float4*)(wsk + (((size_t)li * BH + bh) * NCH + c) * 64 + t * 4);
        {
            int j = e;
            float a8[8];
#pragma unroll
            for (int s = 0; s < 8; ++s) a8[s] = 0.f;
            for (int d0 = 0; d0 < 64; d0 += 4) {
                float4 kf = *(const float4*)(KP + swz4(j, d0));
#pragma unroll
                for (int s = 0; s < 8; ++s) {
                    float4 qf = *(const float4*)(QP + swz4(w + 8 * s, d0));
                    a8[s] += qf.x * kf.x + qf.y * kf.y + qf.z * kf.z + qf.w * kf.w;
                }
            }
#pragma unroll
            for (int s = 0; s < 8; ++s) { int i = w + 8 * s; AA[swz(i, j)] = (j <= i) ? a8[s] : 0.f; }
        }
        __syncthreads();
        if (t < 64) {
            int i = t; float rs = 0.f, qz = 0.f;
            for (int d0 = 0; d0 < 64; d0 += 4) {
                float4 af = *(const float4*)(AA + swz4(i, d0));
                rs += (af.x + af.y) + (af.z + af.w);
                float4 qf = *(const float4*)(QP + swz4(i, d0));
                float4 zf = *(const float4*)(zz + d0);
                qz += qf.x * zf.x + qf.y * zf.y + qf.z * zf.z + qf.w * zf.w;
            }
            nrmT[i] = rs + qz;
        }
        __syncthreads();
        {
            float acc[8];
#pragma unroll
            for (int s = 0; s < 8; ++s) acc[s] = 0.f;
            for (int d0 = 0; d0 < 64; d0 += 4) {
                float4 sf = *(const float4*)(WW + swz4(e, d0));
#pragma unroll
                for (int s = 0; s < 8; ++s) {
                    float4 qf = *(const float4*)(QP + swz4(w + 8 * s, d0));
                    acc[s] += qf.x * sf.x + qf.y * sf.y + qf.z * sf.z + qf.w * sf.w;
                }
            }
            for (int j0 = 0; j0 < 64; j0 += 4) {
                float v0 = VP[swz(j0, e)], v1 = VP[swz(j0 + 1, e)];
                float v2 = VP[swz(j0 + 2, e)], v3 = VP[swz(j0 + 3, e)];
#pragma unroll
                for (int s = 0; s < 8; ++s) {
                    int i = w + 8 * s;
                    if (j0 <= i) {
                        float4 af = *(const float4*)(AA + swz4(i, j0));
                        acc[s] += af.x * v0 + af.y * v1 + af.z * v2 + af.w * v3;
                    }
                }
            }
#pragma unroll
            for (int s = 0; s < 8; ++s) {
                int i = w + 8 * s;
                oacc[s] += swl * (acc[s] / fmaxf(nrmT[i], EPSF));
            }
        }
        __syncthreads();
    }
#pragma unroll
    for (int s = 0; s < 8; ++s) out[cb + (size_t)(w + 8 * s) * 64 + e] = oacc[s];
}

extern "C" void kernel_launch(void* const* d_in, const int* in_sizes, int n_in,
                              void* d_out, int out_size, void* d_ws, size_t ws_size,
                              hipStream_t stream) {
    const float* q  = (const float*)d_in[0];
    const float* k  = (const float*)d_in[1];
    const float* v  = (const float*)d_in[2];
    const float* Wk = (const float*)d_in[3];
    const float* Wv = (const float*)d_in[4];
    const float* sw = (const float*)d_in[5];
    float* out = (float*)d_out;
    float* wsf = (float*)d_ws;
    const size_t kv_per_lvl = 8388608ull;                 // wskv floats per level
    const size_t kst_per_lvl = 131072ull;                 // wsk floats per level
    const size_t proj_all = 33554432ull;                  // wkp (or wvp) floats, all levels
    const size_t med_bytes  = 4ull * (kv_per_lvl + kst_per_lvl) * 4ull;          // ~136 MB
    const size_t full_bytes = med_bytes + 2ull * proj_all * 4ull;                // ~405 MB
    if (ws_size >= full_bytes) {
        float* wskv = wsf;
        float* wsk  = wsf + 4ull * kv_per_lvl;
        float* wkp  = wsk + 4ull * kst_per_lvl;
        float* wvp  = wkp + proj_all;
        phaseA<<<dim3(2048), dim3(512), 0, stream>>>(k, v, Wk, Wv, wskv, wsk, wkp, wvp, 0, 4, 1);
        phaseB<<<dim3(1024), dim3(512), 0, stream>>>(wskv, wsk);
        phaseC2<<<dim3(2048), dim3(512), 0, stream>>>(q, sw, wskv, wsk, wkp, wvp, out);
    } else if (ws_size >= med_bytes) {
        float* wskv = wsf;
        float* wsk  = wsf + 4ull * kv_per_lvl;
        phaseA<<<dim3(2048), dim3(512), 0, stream>>>(k, v, Wk, Wv, wskv, wsk, nullptr, nullptr, 0, 4, 0);
        phaseB<<<dim3(1024), dim3(512), 0, stream>>>(wskv, wsk);
        phaseC<<<dim3(2048), dim3(512), 0, stream>>>(q, k, v, Wk, Wv, sw, wskv, wsk, out, 0, 4, 0);
    } else {
        float* wskv = wsf;
        float* wsk  = wsf + kv_per_lvl;
        for (int l = 0; l < 4; ++l) {
            phaseA<<<dim3(2048), dim3(512), 0, stream>>>(k, v, Wk, Wv, wskv, wsk, nullptr, nullptr, l, 1, 0);
            phaseB<<<dim3(256),  dim3(512), 0, stream>>>(wskv, wsk);
            phaseC<<<dim3(2048), dim3(512), 0, stream>>>(q, k, v, Wk, Wv, sw, wskv, wsk, out, l, 1, l > 0);
        }
    }
}

// Round 13
// 1144.095 us; speedup vs baseline: 1.9811x; 1.9811x over previous
//
#include <hip/hip_runtime.h>

#define BH   32      // B*H
#define NN   4096
#define DD   64
#define CC   64      // chunk rows
#define NCH  64      // NN/CC
#define NL   4
#define EPSF 1e-6f

// ---- swizzled LDS addressing: row stride 64 floats, float4-granular XOR swizzle.
__device__ __forceinline__ int swz(int row, int d) {
    return (row << 6) + ((((d >> 2) ^ (row & 7)) << 2) | (d & 3));
}
__device__ __forceinline__ int swz4(int row, int d0) {   // d0 % 4 == 0
    return (row << 6) + (((d0 >> 2) ^ (row & 7)) << 2);
}
__device__ __forceinline__ float elu1(float x) { return x > 0.f ? x + 1.f : __expf(x); }

// load 64x64 fp32 tile (global, row-major, 16B aligned) into swizzled LDS
__device__ __forceinline__ void load_tile(const float* __restrict__ g, float* buf, int t) {
    for (int m4 = t; m4 < 1024; m4 += 512) {
        int i = m4 >> 4, q = m4 & 15;
        *(float4*)(buf + (i << 6) + ((q ^ (i & 7)) << 2)) = ((const float4*)g)[m4];
    }
}
// inverse: swizzled LDS tile -> global row-major
__device__ __forceinline__ void store_tile(float* __restrict__ g, const float* buf, int t) {
    for (int m4 = t; m4 < 1024; m4 += 512) {
        int i = m4 >> 4, q = m4 & 15;
        ((float4*)g)[m4] = *(const float4*)(buf + (i << 6) + ((q ^ (i & 7)) << 2));
    }
}

// in-place running block-sum update: S_l -> S_{l+1}  (half = 2^l)
__device__ __forceinline__ void update_sums(float* KS, float* VS, int t, int half) {
    for (int m = t; m < 4096; m += 512) {
        int i = m >> 6, d = m & 63;
        if (i & half) {
            int idx = (i & ~(2 * half - 1)) | (half - 1);
            KS[swz(i, d)] += KS[swz(idx, d)];
            VS[swz(i, d)] += VS[swz(idx, d)];
        }
    }
}

// XP[i][e] = (elu?) ( (1/len_i) * sum_d XS[i][d] * W[e][d] )
__device__ __forceinline__ void project(const float* XS, const float* W, float* XP,
                                        int t, int half, bool do_elu) {
    int e = t & 63, w = t >> 6;
    float acc[8];
#pragma unroll
    for (int s = 0; s < 8; ++s) acc[s] = 0.f;
    for (int d0 = 0; d0 < 64; d0 += 4) {
        float4 wf = *(const float4*)(W + swz4(e, d0));       // per-lane row read
#pragma unroll
        for (int s = 0; s < 8; ++s) {
            float4 xf = *(const float4*)(XS + swz4(w + 8 * s, d0));  // broadcast
            acc[s] += xf.x * wf.x + xf.y * wf.y + xf.z * wf.z + xf.w * wf.w;
        }
    }
#pragma unroll
    for (int s = 0; s < 8; ++s) {
        int i = w + 8 * s;
        float rl = 1.f / (float)((i & (2 * half - 1)) + 1);
        float pv = acc[s] * rl;
        XP[swz(i, e)] = do_elu ? elu1(pv) : pv;
    }
}

// ======== Per-level pipeline (primary path; 101 MB workspace) ========

// Phase A1: single level, 4 LDS arrays (64 KB -> 2 WG/CU).
// XX serves as Wk, then VP; Wv loads into dead KS.
__global__ __launch_bounds__(512) void phaseA1(const float* __restrict__ k,
                                               const float* __restrict__ v,
                                               const float* __restrict__ Wk,
                                               const float* __restrict__ Wv,
                                               float* __restrict__ wskv,
                                               float* __restrict__ wsk,
                                               float* __restrict__ wkp,
                                               float* __restrict__ wvp,
                                               int l) {
    __shared__ __align__(16) float KS[4096], VS[4096], KP[4096], XX[4096];
    int t = threadIdx.x;
    int bh = blockIdx.x >> 6, c = blockIdx.x & 63;
    const size_t cb = ((size_t)bh * NN + (size_t)c * CC) * DD;
    load_tile(k + cb, KS, t);
    load_tile(v + cb, VS, t);
    __syncthreads();
    for (int lp = 0; lp <= l; ++lp) { update_sums(KS, VS, t, 1 << lp); __syncthreads(); }
    load_tile(Wk + (size_t)l * 4096, XX, t); __syncthreads();
    project(KS, XX, KP, t, 1 << l, true);  __syncthreads();      // KS dead after this
    store_tile(wkp + cb, KP, t);
    load_tile(Wv + (size_t)l * 4096, KS, t); __syncthreads();    // Wv -> old KS slot
    project(VS, KS, XX, t, 1 << l, false); __syncthreads();      // VP -> XX
    store_tile(wvp + cb, XX, t);
    // chunk sums: wskv[e][d] = sum_i KP[i][d]*VP[i][e];  wsk[d] = sum_i KP[i][d]
    int d = t & 63, eg = t >> 6;
    float acc[8];
#pragma unroll
    for (int u = 0; u < 8; ++u) acc[u] = 0.f;
    float ks = 0.f;
    for (int i = 0; i < 64; ++i) {
        float kp = KP[swz(i, d)];
        float4 va = *(const float4*)(XX + swz4(i, eg * 8));      // broadcast
        float4 vb = *(const float4*)(XX + swz4(i, eg * 8 + 4));  // broadcast
        acc[0] += kp * va.x; acc[1] += kp * va.y; acc[2] += kp * va.z; acc[3] += kp * va.w;
        acc[4] += kp * vb.x; acc[5] += kp * vb.y; acc[6] += kp * vb.z; acc[7] += kp * vb.w;
        ks += kp;
    }
    size_t kvb = ((size_t)(bh * NCH + c)) << 12;
#pragma unroll
    for (int u = 0; u < 8; ++u) wskv[kvb + (size_t)(eg * 8 + u) * 64 + d] = acc[u];
    if (eg == 0) wsk[(size_t)(bh * NCH + c) * 64 + d] = ks;
}

// Phase B1: exclusive prefix over chunks, single level (in place)
__global__ __launch_bounds__(512) void phaseB1(float* __restrict__ wskv, float* __restrict__ wsk) {
    int bh = blockIdx.x >> 3, s = blockIdx.x & 7;
    size_t base = ((size_t)bh << 18) + ((size_t)s << 9) + threadIdx.x;
    float run = 0.f;
    for (int c = 0; c < 64; ++c) {
        size_t a = base + ((size_t)c << 12);
        float vv = wskv[a];
        wskv[a] = run;
        run += vv;
    }
    if (s == 0 && threadIdx.x < 64) {
        size_t b2 = ((size_t)bh << 12) + threadIdx.x;
        float r2 = 0.f;
        for (int c = 0; c < 64; ++c) {
            size_t a = b2 + (size_t)(c << 6);
            float vv = wsk[a];
            wsk[a] = r2;
            r2 += vv;
        }
    }
}

// Phase C21: single-level lean output. 4 LDS arrays (~65.9 KB -> 2 WG/CU).
// Merged GEMM computes A-scores, q.S, q.z in one pass; AA overwrites KP; norm folded.
__global__ __launch_bounds__(512) void phaseC21(const float* __restrict__ q,
                                                const float* __restrict__ sweights,
                                                const float* __restrict__ wskv,
                                                const float* __restrict__ wsk,
                                                const float* __restrict__ wkp,
                                                const float* __restrict__ wvp,
                                                float* __restrict__ out,
                                                int l, int accum) {
    __shared__ __align__(16) float QP[4096], KP[4096], VP[4096], WW[4096];
    __shared__ __align__(16) float zz[64];
    int t = threadIdx.x;
    int bh = blockIdx.x >> 6, c = blockIdx.x & 63;
    const size_t cb = ((size_t)bh * NN + (size_t)c * CC) * DD;
    // qp = elu(q)+1, swizzled into LDS
    for (int m4 = t; m4 < 1024; m4 += 512) {
        int i = m4 >> 4, qq = m4 & 15;
        float4 g = ((const float4*)(q + cb))[m4];
        g.x = elu1(g.x); g.y = elu1(g.y); g.z = elu1(g.z); g.w = elu1(g.w);
        *(float4*)(QP + (i << 6) + ((qq ^ (i & 7)) << 2)) = g;
    }
    load_tile(wkp + cb, KP, t);
    load_tile(wvp + cb, VP, t);
    load_tile(wskv + (((size_t)(bh * NCH + c)) << 12), WW, t);   // S^T tile [e][d]
    if (t < 16) *(float4*)(zz + t * 4) =
        *(const float4*)(wsk + (size_t)(bh * NCH + c) * 64 + t * 4);
    // softmax of scale weights in registers (L2-hot, redundant per thread)
    float s0 = sweights[0], s1 = sweights[1], s2 = sweights[2], s3 = sweights[3];
    float mx = fmaxf(fmaxf(s0, s1), fmaxf(s2, s3));
    float e0 = __expf(s0 - mx), e1 = __expf(s1 - mx), e2 = __expf(s2 - mx), e3 = __expf(s3 - mx);
    float inv = 1.f / (e0 + e1 + e2 + e3);
    float swl = ((l == 0) ? e0 : (l == 1) ? e1 : (l == 2) ? e2 : e3) * inv;
    int e = t & 63, w = t >> 6;
    float oacc[8];
    if (accum) {
#pragma unroll
        for (int s = 0; s < 8; ++s) oacc[s] = out[cb + (size_t)(w + 8 * s) * 64 + e];
    } else {
#pragma unroll
        for (int s = 0; s < 8; ++s) oacc[s] = 0.f;
    }
    __syncthreads();
    // merged GEMM: a8 = A[i][e], acc = (q.S)[e], nrm = q.z
    float a8[8], acc[8], nrm[8];
#pragma unroll
    for (int s = 0; s < 8; ++s) { a8[s] = 0.f; acc[s] = 0.f; nrm[s] = 0.f; }
    for (int d0 = 0; d0 < 64; d0 += 4) {
        float4 kf = *(const float4*)(KP + swz4(e, d0));       // per-lane row e
        float4 sf = *(const float4*)(WW + swz4(e, d0));       // per-lane row e (S^T)
        float4 zf = *(const float4*)(zz + d0);                // broadcast
#pragma unroll
        for (int s = 0; s < 8; ++s) {
            float4 qf = *(const float4*)(QP + swz4(w + 8 * s, d0));  // broadcast
            a8[s]  += qf.x * kf.x + qf.y * kf.y + qf.z * kf.z + qf.w * kf.w;
            acc[s] += qf.x * sf.x + qf.y * sf.y + qf.z * sf.z + qf.w * sf.w;
            nrm[s] += qf.x * zf.x + qf.y * zf.y + qf.z * zf.z + qf.w * zf.w;
        }
    }
    __syncthreads();   // all KP reads done; safe to overwrite with AA
#pragma unroll
    for (int s = 0; s < 8; ++s) { int i = w + 8 * s; KP[swz(i, e)] = (e <= i) ? a8[s] : 0.f; }
    __syncthreads();   // AA visible
    // A·V + rowsum(A) folded (upper triangle zero-padded)
    for (int j0 = 0; j0 < 64; j0 += 4) {
        float v0 = VP[swz(j0, e)], v1 = VP[swz(j0 + 1, e)];
        float v2 = VP[swz(j0 + 2, e)], v3 = VP[swz(j0 + 3, e)];
#pragma unroll
        for (int s = 0; s < 8; ++s) {
            int i = w + 8 * s;
            if (j0 <= i) {                                    // wave-uniform
                float4 af = *(const float4*)(KP + swz4(i, j0));  // broadcast (AA row)
                acc[s] += af.x * v0 + af.y * v1 + af.z * v2 + af.w * v3;
                nrm[s] += (af.x + af.y) + (af.z + af.w);
            }
        }
    }
#pragma unroll
    for (int s = 0; s < 8; ++s) oacc[s] += swl * (acc[s] / fmaxf(nrm[s], EPSF));
#pragma unroll
    for (int s = 0; s < 8; ++s) out[cb + (size_t)(w + 8 * s) * 64 + e] = oacc[s];
}

// ======== Fallback (SPLIT) kernels — proven round-3 versions ========

__global__ __launch_bounds__(512) void phaseA(const float* __restrict__ k,
                                              const float* __restrict__ v,
                                              const float* __restrict__ Wk,
                                              const float* __restrict__ Wv,
                                              float* __restrict__ wskv,
                                              float* __restrict__ wsk,
                                              int lbase, int nlev) {
    __shared__ __align__(16) float KS[4096], VS[4096], KP[4096], VP[4096], WW[4096];
    int t = threadIdx.x;
    int bh = blockIdx.x >> 6, c = blockIdx.x & 63;
    const size_t cb = ((size_t)bh * NN + (size_t)c * CC) * DD;
    load_tile(k + cb, KS, t);
    load_tile(v + cb, VS, t);
    __syncthreads();
    for (int lp = 0; lp < lbase; ++lp) { update_sums(KS, VS, t, 1 << lp); __syncthreads(); }
    for (int li = 0; li < nlev; ++li) {
        int l = lbase + li;
        update_sums(KS, VS, t, 1 << l); __syncthreads();
        load_tile(Wk + (size_t)l * 4096, WW, t); __syncthreads();
        project(KS, WW, KP, t, 1 << l, true);  __syncthreads();
        load_tile(Wv + (size_t)l * 4096, WW, t); __syncthreads();
        project(VS, WW, VP, t, 1 << l, false); __syncthreads();
        int d = t & 63, eg = t >> 6;
        float acc[8];
#pragma unroll
        for (int u = 0; u < 8; ++u) acc[u] = 0.f;
        float ks = 0.f;
        for (int i = 0; i < 64; ++i) {
            float kp = KP[swz(i, d)];
            float4 va = *(const float4*)(VP + swz4(i, eg * 8));
            float4 vb = *(const float4*)(VP + swz4(i, eg * 8 + 4));
            acc[0] += kp * va.x; acc[1] += kp * va.y; acc[2] += kp * va.z; acc[3] += kp * va.w;
            acc[4] += kp * vb.x; acc[5] += kp * vb.y; acc[6] += kp * vb.z; acc[7] += kp * vb.w;
            ks += kp;
        }
        size_t kvb = ((((size_t)li * BH + bh) * NCH) + c) << 12;
#pragma unroll
        for (int u = 0; u < 8; ++u) wskv[kvb + (size_t)(eg * 8 + u) * 64 + d] = acc[u];
        if (eg == 0) wsk[(((size_t)li * BH + bh) * NCH + c) * 64 + d] = ks;
        __syncthreads();
    }
}

__global__ __launch_bounds__(512) void phaseC(const float* __restrict__ q,
                                              const float* __restrict__ k,
                                              const float* __restrict__ v,
                                              const float* __restrict__ Wk,
                                              const float* __restrict__ Wv,
                                              const float* __restrict__ sweights,
                                              const float* __restrict__ wskv,
                                              const float* __restrict__ wsk,
                                              float* __restrict__ out,
                                              int lbase, int nlev, int accum) {
    __shared__ __align__(16) float QP[4096], KS[4096], VS[4096], KP[4096], VP[4096], WW[4096], AA[4096];
    __shared__ __align__(16) float zz[64];
    __shared__ float nrmT[64];
    __shared__ float swsh[NL];
    int t = threadIdx.x;
    int bh = blockIdx.x >> 6, c = blockIdx.x & 63;
    const size_t cb = ((size_t)bh * NN + (size_t)c * CC) * DD;
    for (int m4 = t; m4 < 1024; m4 += 512) {
        int i = m4 >> 4, qq = m4 & 15;
        float4 g = ((const float4*)(q + cb))[m4];
        g.x = elu1(g.x); g.y = elu1(g.y); g.z = elu1(g.z); g.w = elu1(g.w);
        *(float4*)(QP + (i << 6) + ((qq ^ (i & 7)) << 2)) = g;
    }
    load_tile(k + cb, KS, t);
    load_tile(v + cb, VS, t);
    if (t == 0) {
        float s0 = sweights[0], s1 = sweights[1], s2 = sweights[2], s3 = sweights[3];
        float mx = fmaxf(fmaxf(s0, s1), fmaxf(s2, s3));
        float e0 = __expf(s0 - mx), e1 = __expf(s1 - mx), e2 = __expf(s2 - mx), e3 = __expf(s3 - mx);
        float inv = 1.f / (e0 + e1 + e2 + e3);
        swsh[0] = e0 * inv; swsh[1] = e1 * inv; swsh[2] = e2 * inv; swsh[3] = e3 * inv;
    }
    int e = t & 63, w = t >> 6;
    float oacc[8];
    if (accum) {
#pragma unroll
        for (int s = 0; s < 8; ++s) oacc[s] = out[cb + (size_t)(w + 8 * s) * 64 + e];
    } else {
#pragma unroll
        for (int s = 0; s < 8; ++s) oacc[s] = 0.f;
    }
    __syncthreads();
    for (int lp = 0; lp < lbase; ++lp) { update_sums(KS, VS, t, 1 << lp); __syncthreads(); }
    for (int li = 0; li < nlev; ++li) {
        int l = lbase + li;
        float swl = swsh[l];
        update_sums(KS, VS, t, 1 << l); __syncthreads();
        load_tile(Wk + (size_t)l * 4096, WW, t); __syncthreads();
        project(KS, WW, KP, t, 1 << l, true);  __syncthreads();
        load_tile(Wv + (size_t)l * 4096, WW, t); __syncthreads();
        project(VS, WW, VP, t, 1 << l, false); __syncthreads();
        size_t kvb = ((((size_t)li * BH + bh) * NCH) + c) << 12;
        for (int m4 = t; m4 < 1024; m4 += 512) {
            int ee = m4 >> 4, qq = m4 & 15;
            *(float4*)(WW + (ee << 6) + ((qq ^ (ee & 7)) << 2)) = *(const float4*)(wskv + kvb + ((size_t)m4 << 2));
        }
        if (t < 16) *(float4*)(zz + t * 4) =
            *(const float4*)(wsk + (((size_t)li * BH + bh) * NCH + c) * 64 + t * 4);
        {
            int j = e;
            float a8[8];
#pragma unroll
            for (int s = 0; s < 8; ++s) a8[s] = 0.f;
            for (int d0 = 0; d0 < 64; d0 += 4) {
                float4 kf = *(const float4*)(KP + swz4(j, d0));
#pragma unroll
                for (int s = 0; s < 8; ++s) {
                    float4 qf = *(const float4*)(QP + swz4(w + 8 * s, d0));
                    a8[s] += qf.x * kf.x + qf.y * kf.y + qf.z * kf.z + qf.w * kf.w;
                }
            }
#pragma unroll
            for (int s = 0; s < 8; ++s) { int i = w + 8 * s; AA[swz(i, j)] = (j <= i) ? a8[s] : 0.f; }
        }
        __syncthreads();
        if (t < 64) {
            int i = t; float rs = 0.f, qz = 0.f;
            for (int d0 = 0; d0 < 64; d0 += 4) {
                float4 af = *(const float4*)(AA + swz4(i, d0));
                rs += (af.x + af.y) + (af.z + af.w);
                float4 qf = *(const float4*)(QP + swz4(i, d0));
                float4 zf = *(const float4*)(zz + d0);
                qz += qf.x * zf.x + qf.y * zf.y + qf.z * zf.z + qf.w * zf.w;
            }
            nrmT[i] = rs + qz;
        }
        __syncthreads();
        {
            float acc[8];
#pragma unroll
            for (int s = 0; s < 8; ++s) acc[s] = 0.f;
            for (int d0 = 0; d0 < 64; d0 += 4) {
                float4 sf = *(const float4*)(WW + swz4(e, d0));
#pragma unroll
                for (int s = 0; s < 8; ++s) {
                    float4 qf = *(const float4*)(QP + swz4(w + 8 * s, d0));
                    acc[s] += qf.x * sf.x + qf.y * sf.y + qf.z * sf.z + qf.w * sf.w;
                }
            }
            for (int j0 = 0; j0 < 64; j0 += 4) {
                float v0 = VP[swz(j0, e)], v1 = VP[swz(j0 + 1, e)];
                float v2 = VP[swz(j0 + 2, e)], v3 = VP[swz(j0 + 3, e)];
#pragma unroll
                for (int s = 0; s < 8; ++s) {
                    int i = w + 8 * s;
                    if (j0 <= i) {
                        float4 af = *(const float4*)(AA + swz4(i, j0));
                        acc[s] += af.x * v0 + af.y * v1 + af.z * v2 + af.w * v3;
                    }
                }
            }
#pragma unroll
            for (int s = 0; s < 8; ++s) {
                int i = w + 8 * s;
                oacc[s] += swl * (acc[s] / fmaxf(nrmT[i], EPSF));
            }
        }
        __syncthreads();
    }
#pragma unroll
    for (int s = 0; s < 8; ++s) out[cb + (size_t)(w + 8 * s) * 64 + e] = oacc[s];
}

extern "C" void kernel_launch(void* const* d_in, const int* in_sizes, int n_in,
                              void* d_out, int out_size, void* d_ws, size_t ws_size,
                              hipStream_t stream) {
    const float* q  = (const float*)d_in[0];
    const float* k  = (const float*)d_in[1];
    const float* v  = (const float*)d_in[2];
    const float* Wk = (const float*)d_in[3];
    const float* Wv = (const float*)d_in[4];
    const float* sw = (const float*)d_in[5];
    float* out = (float*)d_out;
    float* wsf = (float*)d_ws;
    const size_t lvl_f  = 8388608ull;    // wskv floats per level (= wkp = wvp floats)
    const size_t kst_f  = 131072ull;     // wsk floats per level
    const size_t need_f = 3ull * lvl_f + kst_f;           // 101 MB
    if (ws_size >= need_f * 4ull) {
        float* wskv = wsf;
        float* wsk  = wskv + lvl_f;
        float* wkp  = wsk + kst_f;
        float* wvp  = wkp + lvl_f;
        for (int l = 0; l < NL; ++l) {
            phaseA1<<<dim3(2048), dim3(512), 0, stream>>>(k, v, Wk, Wv, wskv, wsk, wkp, wvp, l);
            phaseB1<<<dim3(256),  dim3(512), 0, stream>>>(wskv, wsk);
            phaseC21<<<dim3(2048), dim3(512), 0, stream>>>(q, sw, wskv, wsk, wkp, wvp, out, l, l > 0);
        }
    } else {
        float* wskv = wsf;
        float* wsk  = wsf + lvl_f;
        for (int l = 0; l < NL; ++l) {
            phaseA<<<dim3(2048), dim3(512), 0, stream>>>(k, v, Wk, Wv, wskv, wsk, l, 1);
            phaseB1<<<dim3(256), dim3(512), 0, stream>>>(wskv, wsk);
            phaseC<<<dim3(2048), dim3(512), 0, stream>>>(q, k, v, Wk, Wv, sw, wskv, wsk, out, l, 1, l > 0);
        }
    }
}